// Round 4
// baseline (389.103 us; speedup 1.0000x reference)
//
#include <hip/hip_runtime.h>
#include <math.h>

// NPTransitionPrior: B=64, T=514, D=32, H=128, LAGS=2, IN=65
// out (fp32): residuals (64*512*32) | sumlogdet (64) | hist_jac (32*32768*64)
//
// R4 = R3 + epilogue LDS-read hoisting + phase-2 ks=0 B-frag prefetch.
//  - epilogue: b1/W2/0.01*W2/w64/yy loaded ONCE into registers per wave
//    (compiler could not CSE the ~96 redundant ds_read_b32 across nt because
//    of intervening gp stores to L_GB). Leaky slope now a cndmask select.
//    Arithmetic bit-identical to R3.
//  - phase-2 ks=0 bF fragments prefetched before the epilogue: global latency
//    hides under epilogue VALU instead of serializing after the barrier.
//  - all layouts / barriers / stores identical to R3 (369us end-to-end).

typedef _Float16 f16;
typedef __attribute__((ext_vector_type(8))) _Float16 half8;
typedef __attribute__((ext_vector_type(4))) _Float16 half4;
typedef __attribute__((ext_vector_type(4))) float floatx4;

namespace {
// ---- workspace layout (bytes) ----
constexpr size_t W1F_SZ    = (size_t)32 * 8192 * 2;              // 524,288 per array
constexpr size_t WS_W1F_HI = 0;
constexpr size_t WS_W1F_LO = W1F_SZ;                             // 524,288
constexpr size_t WS_W1TF   = 2 * W1F_SZ;                         // 1,048,576
constexpr size_t WS_W64    = 3 * W1F_SZ;                         // 1,572,864 (32*128 f32)
constexpr size_t WS_RES    = WS_W64 + (size_t)32 * 128 * 4;      // 1,589,248 (4 MB)
// total ws need: WS_RES + 64*512*32*4 = 5,783,552 bytes  (< proven 7,000,064)

constexpr int XS_ROW = 40;   // f16 per padded x row (32+8)
constexpr int GB_HP  = 136;  // halves per GB row (128+8) -> odd 16B units, b128-clean

// ---- LDS layout (bytes) ----
constexpr int L_GB   = 0;                  // 64*136*2 = 17408
constexpr int L_XSHI = 17408;              // 66*40*2 = 5280
constexpr int L_XSLO = L_XSHI + 5280;      // 22688
constexpr int L_B1   = L_XSLO + 5280;      // 27968 (128 f32)
constexpr int L_W2   = L_B1 + 512;
constexpr int L_W64  = L_W2 + 512;
constexpr int L_YY   = L_W64 + 512;        // 64 f32
constexpr int L_RES  = L_YY + 256;         // 4*64 f32
constexpr int L_JAC  = L_RES + 1024;
constexpr int L_TOTAL = L_JAC + 1024;      // 31808 bytes -> up to 5 blocks/CU

constexpr size_t OUT1_OFF = (size_t)64 * 512 * 32;   // 1048576
constexpr size_t OUT2_OFF = OUT1_OFF + 64;
}

// ---- split W1[:, :, :64] into FRAGMENT-LINEAR layouts ----
// phase-1 A frags: [d][hblk=h>>4][ks=k>>5][lane=q*16+(h&15)][j=k&7]  (hi and lo)
// phase-2 B frags: [d][ks=h>>5][kt=k>>4][lane=q2*16+(k&15)][j=h&7]   (hi only)
// Each wave-load in main is then one contiguous, coalesced 1KB global_load_dwordx4.
__global__ __launch_bounds__(256) void split_w1_kernel(
    const float* __restrict__ W1, f16* __restrict__ wh, f16* __restrict__ wl,
    f16* __restrict__ wT, float* __restrict__ w64)
{
    int idx = blockIdx.x * 256 + threadIdx.x;
    if (idx >= 32 * 128 * 64) return;
    int d = idx >> 13, rem = idx & 8191;
    int h = rem >> 6, k = rem & 63;
    float v = W1[((size_t)(d * 128 + h)) * 65 + k];
    f16 hi = (f16)v;
    float r = v - (float)hi;
    int lane1 = (((k >> 3) & 3) << 4) | (h & 15);
    size_t o1 = ((((size_t)d * 8 + (h >> 4)) * 2 + (k >> 5)) * 64 + lane1) * 8 + (k & 7);
    wh[o1] = hi;
    wl[o1] = (f16)(r * 4096.0f);
    int lane2 = (((h >> 3) & 3) << 4) | (k & 15);
    size_t o2 = ((((size_t)d * 4 + (h >> 5)) * 4 + (k >> 4)) * 64 + lane2) * 8 + (h & 7);
    wT[o2] = hi;
    if (k == 63) w64[d * 128 + h] = W1[((size_t)(d * 128 + h)) * 65 + 64];
}

__global__ __launch_bounds__(256, 4) void np_main_kernel(
    const float* __restrict__ x,    // (64,514,32)
    const float* __restrict__ b1,   // (32,128)
    const float* __restrict__ W2,   // (32,128)
    const float* __restrict__ b2,   // (32,)
    const char* __restrict__ ws,
    float* __restrict__ resw,       // d-major residuals (32, 32768)
    float* __restrict__ out)
{
    extern __shared__ char smem[];
    const int tile = blockIdx.x;          // 0..511
    const int d    = blockIdx.y;          // 0..31
    const int b    = tile >> 3;
    const int t0   = (tile & 7) << 6;     // 64-window tile
    const int tid  = threadIdx.x;
    const int wave = tid >> 6, lane = tid & 63;
    const int c = lane & 15, q = lane >> 4;

    float* b1L  = (float*)(smem + L_B1);
    float* W2L  = (float*)(smem + L_W2);
    float* w64L = (float*)(smem + L_W64);
    float* yyL  = (float*)(smem + L_YY);
    float* resP = (float*)(smem + L_RES);
    float* jacP = (float*)(smem + L_JAC);

    const f16* w1fh = (const f16*)(ws + WS_W1F_HI) + (size_t)d * 8192;
    const f16* w1fl = (const f16*)(ws + WS_W1F_LO) + (size_t)d * 8192;
    const f16* w1tf = (const f16*)(ws + WS_W1TF)   + (size_t)d * 8192;
    const float* w64p = (const float*)(ws + WS_W64);

    // ---------- stage: x tile (f32 global, L2-hot) split to hi/lo f16 in LDS ----------
    {
        const float4* xs = (const float4*)(x + (size_t)(b * 514 + t0) * 32);
        for (int u = tid; u < 528; u += 256) {          // 66 rows x 8 float4
            float4 v = xs[u];
            int row = u >> 3, c4 = u & 7;
            half4 hi, lo;
            #pragma unroll
            for (int j = 0; j < 4; ++j) {
                float vv = (&v.x)[j];
                f16 h = (f16)vv;
                hi[j] = h;
                lo[j] = (f16)((vv - (float)h) * 4096.0f);
            }
            *(half4*)(smem + L_XSHI + (row * XS_ROW + c4 * 4) * 2) = hi;
            *(half4*)(smem + L_XSLO + (row * XS_ROW + c4 * 4) * 2) = lo;
        }
        if (tid < 128) {
            b1L[tid]  = b1[d * 128 + tid];
            W2L[tid]  = W2[d * 128 + tid];
            w64L[tid] = w64p[d * 128 + tid];
        }
        if (tid < 64) yyL[tid] = x[(size_t)(b * 514 + t0 + tid + 2) * 32 + d];
    }
    __syncthreads();

    // ---------- phase 1: pre[h,n], M=h(wave owns 32), N=n(64), K=64 ----------
    // A fragments straight from global (fragment-linear ws), B from LDS.
    floatx4 accP[2][4], accQ[2][4];
    #pragma unroll
    for (int ht = 0; ht < 2; ++ht)
        #pragma unroll
        for (int nt = 0; nt < 4; ++nt) { accP[ht][nt] = (floatx4)0.f; accQ[ht][nt] = (floatx4)0.f; }

    #pragma unroll
    for (int ks = 0; ks < 2; ++ks) {
        half8 aH[2], aL[2], bH[4], bL[4];
        #pragma unroll
        for (int ht = 0; ht < 2; ++ht) {
            const int fo = (((wave * 2 + ht) * 2 + ks) * 64 + lane) * 8;
            aH[ht] = *(const half8*)(w1fh + fo);
            aL[ht] = *(const half8*)(w1fl + fo);
        }
        #pragma unroll
        for (int nt = 0; nt < 4; ++nt) {
            const int off = (nt * 16 + c + ks) * XS_ROW + q * 8;  // window overlap trick
            bH[nt] = *(const half8*)(smem + L_XSHI + off * 2);
            bL[nt] = *(const half8*)(smem + L_XSLO + off * 2);
        }
        #pragma unroll
        for (int ht = 0; ht < 2; ++ht)
            #pragma unroll
            for (int nt = 0; nt < 4; ++nt) {
                accP[ht][nt] = __builtin_amdgcn_mfma_f32_16x16x32_f16(aH[ht], bH[nt], accP[ht][nt], 0, 0, 0);
                accQ[ht][nt] = __builtin_amdgcn_mfma_f32_16x16x32_f16(aH[ht], bL[nt], accQ[ht][nt], 0, 0, 0);
                accQ[ht][nt] = __builtin_amdgcn_mfma_f32_16x16x32_f16(aL[ht], bH[nt], accQ[ht][nt], 0, 0, 0);
            }
    }
    // no barrier needed: GB region is disjoint from XS; GB writes are per-wave columns

    // ---------- prefetch phase-2 ks=0 B-fragments (hide HBM/L2 latency under epilogue) ----------
    half8 bF0[4];
    #pragma unroll
    for (int kt = 0; kt < 4; ++kt)
        bF0[kt] = *(const half8*)(w1tf + ((0 * 4 + kt) * 64 + lane) * 8);

    // ---------- hoist wave-invariant LDS scalars into registers ----------
    float b1v[2][4], W2a[2][4], W2b[2][4], w64v[2][4];
    #pragma unroll
    for (int ht = 0; ht < 2; ++ht) {
        const int hbase = wave * 32 + ht * 16 + q * 4;
        #pragma unroll
        for (int r = 0; r < 4; ++r) {
            const int h = hbase + r;
            b1v[ht][r]  = b1L[h];
            float w2    = W2L[h];
            W2a[ht][r]  = w2;
            W2b[ht][r]  = 0.01f * w2;
            w64v[ht][r] = w64L[h];
        }
    }
    float yyv[4];
    #pragma unroll
    for (int nt = 0; nt < 4; ++nt) yyv[nt] = yyL[nt * 16 + c];

    // ---------- epilogue: pre -> g (LDS, A-layout), res/jac64 partials ----------
    float res[4] = {0.f, 0.f, 0.f, 0.f}, j64[4] = {0.f, 0.f, 0.f, 0.f};
    #pragma unroll
    for (int ht = 0; ht < 2; ++ht) {
        const int hbase = wave * 32 + ht * 16 + q * 4;   // D row = q*4 + reg
        #pragma unroll
        for (int nt = 0; nt < 4; ++nt) {
            const int n = nt * 16 + c;                   // D col = lane&15
            half4 gp;
            #pragma unroll
            for (int r = 0; r < 4; ++r) {
                const float pre = accP[ht][nt][r] + accQ[ht][nt][r] * (1.0f / 4096.0f)
                                + b1v[ht][r] + yyv[nt] * w64v[ht][r];
                const float gg = (pre >= 0.f) ? W2a[ht][r] : W2b[ht][r];
                res[nt] += pre * gg;
                j64[nt] += gg * w64v[ht][r];
                gp[r] = (f16)gg;
            }
            *(half4*)(smem + L_GB + (n * GB_HP + hbase) * 2) = gp;
        }
    }
    #pragma unroll
    for (int nt = 0; nt < 4; ++nt) {
        float rv = res[nt];
        rv += __shfl_xor(rv, 16, 64);
        rv += __shfl_xor(rv, 32, 64);
        float jv = j64[nt];
        jv += __shfl_xor(jv, 16, 64);
        jv += __shfl_xor(jv, 32, 64);
        if (lane < 16) {
            resP[wave * 64 + nt * 16 + lane] = rv;
            jacP[wave * 64 + nt * 16 + lane] = jv;
        }
    }
    __syncthreads();

    // ---------- residuals (d-major, coalesced) + logabsdet (one wave) ----------
    if (tid < 64) {
        const int n = tid;
        float r = b2[d], j = 0.f;
        #pragma unroll
        for (int w = 0; w < 4; ++w) { r += resP[w * 64 + n]; j += jacP[w * 64 + n]; }
        resw[(size_t)d * 32768 + (size_t)(b * 512 + t0) + n] = r;
        float lg = logf(fabsf(j));
        #pragma unroll
        for (int off = 32; off > 0; off >>= 1) lg += __shfl_down(lg, off, 64);
        if (tid == 0) atomicAdd(out + OUT1_OFF + b, lg);
    }

    // ---------- phase 2: jac[n, k<64] = g . W1 ; wave owns one 16-n tile ----------
    // A from LDS (GB), B fragments from global (ks=0 prefetched above).
    floatx4 acc2[4];
    #pragma unroll
    for (int kt = 0; kt < 4; ++kt) acc2[kt] = (floatx4)0.f;
    #pragma unroll
    for (int ks = 0; ks < 4; ++ks) {
        const half8 aF = *(const half8*)(smem + L_GB + ((wave * 16 + c) * GB_HP + ks * 32 + q * 8) * 2);
        #pragma unroll
        for (int kt = 0; kt < 4; ++kt) {
            const half8 bFk = (ks == 0) ? bF0[kt]
                            : *(const half8*)(w1tf + ((ks * 4 + kt) * 64 + lane) * 8);
            acc2[kt] = __builtin_amdgcn_mfma_f32_16x16x32_f16(aF, bFk, acc2[kt], 0, 0, 0);
        }
    }

    // ---------- store: transpose 16x64 tile through own (dead) GB slice,
    //            then 4x contiguous global_store_dwordx4 per lane ----------
    {
        float* tp = (float*)(smem + L_GB + wave * (16 * GB_HP * 2));  // 16 rows, stride 68 f32
        #pragma unroll
        for (int kt = 0; kt < 4; ++kt)
            #pragma unroll
            for (int r = 0; r < 4; ++r)
                tp[(q * 4 + r) * 68 + kt * 16 + c] = acc2[kt][r];
        // same-wave DS ordering + data dependency through acc2: no barrier needed
        float* out2 = out + OUT2_OFF + (size_t)d * ((size_t)32768 * 64)
                    + (size_t)(b * 512 + t0 + wave * 16) * 64;
        #pragma unroll
        for (int j = 0; j < 4; ++j) {
            floatx4 v = *(const floatx4*)(tp + (j * 4 + q) * 68 + c * 4);
            *(floatx4*)(out2 + (size_t)j * 256 + (size_t)lane * 4) = v;
        }
    }
}

// ---- residuals: (d, bn) d-major ws -> (bn, d) out, fully coalesced both sides ----
__global__ __launch_bounds__(256) void finish_res_kernel(
    const float* __restrict__ resw, float* __restrict__ out)
{
    __shared__ float tile[32][65];
    const int n0 = blockIdx.x * 64;   // 512 blocks
    const int tid = threadIdx.x;
    #pragma unroll
    for (int i = 0; i < 8; ++i) {
        int idx = i * 256 + tid;              // 0..2047
        int dd = idx >> 6, n = idx & 63;
        tile[dd][n] = resw[(size_t)dd * 32768 + n0 + n];
    }
    __syncthreads();
    #pragma unroll
    for (int i = 0; i < 8; ++i) {
        int idx = i * 256 + tid;
        int n = idx >> 5, dd = idx & 31;
        out[(size_t)(n0 + n) * 32 + dd] = tile[dd][n];
    }
}

extern "C" void kernel_launch(void* const* d_in, const int* in_sizes, int n_in,
                              void* d_out, int out_size, void* d_ws, size_t ws_size,
                              hipStream_t stream) {
    const float* x  = (const float*)d_in[0];
    const float* W1 = (const float*)d_in[1];
    const float* b1 = (const float*)d_in[2];
    const float* W2 = (const float*)d_in[3];
    const float* b2 = (const float*)d_in[4];
    float* out = (float*)d_out;
    char* ws = (char*)d_ws;

    hipMemsetAsync(out + OUT1_OFF, 0, 64 * sizeof(float), stream);

    hipLaunchKernelGGL(split_w1_kernel, dim3((32 * 128 * 64 + 255) / 256), dim3(256), 0, stream,
                       W1, (f16*)(ws + WS_W1F_HI), (f16*)(ws + WS_W1F_LO),
                       (f16*)(ws + WS_W1TF), (float*)(ws + WS_W64));

    hipLaunchKernelGGL(np_main_kernel, dim3(512, 32), dim3(256), L_TOTAL, stream,
                       x, b1, W2, b2, (const char*)ws, (float*)(ws + WS_RES), out);

    hipLaunchKernelGGL(finish_res_kernel, dim3(512), dim3(256), 0, stream,
                       (const float*)(ws + WS_RES), out);
}

// Round 5
// 362.689 us; speedup vs baseline: 1.0728x; 1.0728x over previous
//
#include <hip/hip_runtime.h>
#include <math.h>

// NPTransitionPrior: B=64, T=514, D=32, H=128, LAGS=2, IN=65
// out (fp32): residuals (64*512*32) | sumlogdet (64) | hist_jac (32*32768*64)
//
// R5 = R3 with phase-1 split into two ht-passes (accumulator halving).
//  Occupancy math: R3 unified reg footprint = 72 VGPR + 64 acc = 136 -> 3
//  waves/SIMD (37.5% ceiling, ~31% measured). Halving live accumulators to 32
//  (epilogue consumes them per-ht anyway) targets <=128 -> 4-5 waves/SIMD;
//  LDS (31,808 B) allows 5 blocks/CU. Cost: B-frags re-read per ht (+16
//  ds_read_b128/wave) -- cheap vs the occupancy gain on a latency-bound kernel.
//  Per-ht scalar hoist (16 short-lived regs) removes ~80 redundant ds_read_b32
//  that gp-store aliasing blocked from CSE. R4's cross-barrier bF0 prefetch
//  dropped (regression: +52 long-lived regs -> 2 waves/SIMD).
//  Accumulation order per acc unchanged (ks0->ks1): bit-identical numerics.

typedef _Float16 f16;
typedef __attribute__((ext_vector_type(8))) _Float16 half8;
typedef __attribute__((ext_vector_type(4))) _Float16 half4;
typedef __attribute__((ext_vector_type(4))) float floatx4;

namespace {
// ---- workspace layout (bytes) ----
constexpr size_t W1F_SZ    = (size_t)32 * 8192 * 2;              // 524,288 per array
constexpr size_t WS_W1F_HI = 0;
constexpr size_t WS_W1F_LO = W1F_SZ;                             // 524,288
constexpr size_t WS_W1TF   = 2 * W1F_SZ;                         // 1,048,576
constexpr size_t WS_W64    = 3 * W1F_SZ;                         // 1,572,864 (32*128 f32)
constexpr size_t WS_RES    = WS_W64 + (size_t)32 * 128 * 4;      // 1,589,248 (4 MB)
// total ws need: WS_RES + 64*512*32*4 = 5,783,552 bytes  (< proven 7,000,064)

constexpr int XS_ROW = 40;   // f16 per padded x row (32+8)
constexpr int GB_HP  = 136;  // halves per GB row (128+8) -> odd 16B units, b128-clean

// ---- LDS layout (bytes) ----
constexpr int L_GB   = 0;                  // 64*136*2 = 17408
constexpr int L_XSHI = 17408;              // 66*40*2 = 5280
constexpr int L_XSLO = L_XSHI + 5280;      // 22688
constexpr int L_B1   = L_XSLO + 5280;      // 27968 (128 f32)
constexpr int L_W2   = L_B1 + 512;
constexpr int L_W64  = L_W2 + 512;
constexpr int L_YY   = L_W64 + 512;        // 64 f32
constexpr int L_RES  = L_YY + 256;         // 4*64 f32
constexpr int L_JAC  = L_RES + 1024;
constexpr int L_TOTAL = L_JAC + 1024;      // 31808 bytes -> up to 5 blocks/CU

constexpr size_t OUT1_OFF = (size_t)64 * 512 * 32;   // 1048576
constexpr size_t OUT2_OFF = OUT1_OFF + 64;
}

// ---- split W1[:, :, :64] into FRAGMENT-LINEAR layouts ----
// phase-1 A frags: [d][hblk=h>>4][ks=k>>5][lane=q*16+(h&15)][j=k&7]  (hi and lo)
// phase-2 B frags: [d][ks=h>>5][kt=k>>4][lane=q2*16+(k&15)][j=h&7]   (hi only)
// Each wave-load in main is then one contiguous, coalesced 1KB global_load_dwordx4.
__global__ __launch_bounds__(256) void split_w1_kernel(
    const float* __restrict__ W1, f16* __restrict__ wh, f16* __restrict__ wl,
    f16* __restrict__ wT, float* __restrict__ w64)
{
    int idx = blockIdx.x * 256 + threadIdx.x;
    if (idx >= 32 * 128 * 64) return;
    int d = idx >> 13, rem = idx & 8191;
    int h = rem >> 6, k = rem & 63;
    float v = W1[((size_t)(d * 128 + h)) * 65 + k];
    f16 hi = (f16)v;
    float r = v - (float)hi;
    int lane1 = (((k >> 3) & 3) << 4) | (h & 15);
    size_t o1 = ((((size_t)d * 8 + (h >> 4)) * 2 + (k >> 5)) * 64 + lane1) * 8 + (k & 7);
    wh[o1] = hi;
    wl[o1] = (f16)(r * 4096.0f);
    int lane2 = (((h >> 3) & 3) << 4) | (k & 15);
    size_t o2 = ((((size_t)d * 4 + (h >> 5)) * 4 + (k >> 4)) * 64 + lane2) * 8 + (h & 7);
    wT[o2] = hi;
    if (k == 63) w64[d * 128 + h] = W1[((size_t)(d * 128 + h)) * 65 + 64];
}

__global__ __launch_bounds__(256, 4) void np_main_kernel(
    const float* __restrict__ x,    // (64,514,32)
    const float* __restrict__ b1,   // (32,128)
    const float* __restrict__ W2,   // (32,128)
    const float* __restrict__ b2,   // (32,)
    const char* __restrict__ ws,
    float* __restrict__ resw,       // d-major residuals (32, 32768)
    float* __restrict__ out)
{
    extern __shared__ char smem[];
    const int tile = blockIdx.x;          // 0..511
    const int d    = blockIdx.y;          // 0..31
    const int b    = tile >> 3;
    const int t0   = (tile & 7) << 6;     // 64-window tile
    const int tid  = threadIdx.x;
    const int wave = tid >> 6, lane = tid & 63;
    const int c = lane & 15, q = lane >> 4;

    float* b1L  = (float*)(smem + L_B1);
    float* W2L  = (float*)(smem + L_W2);
    float* w64L = (float*)(smem + L_W64);
    float* yyL  = (float*)(smem + L_YY);
    float* resP = (float*)(smem + L_RES);
    float* jacP = (float*)(smem + L_JAC);

    const f16* w1fh = (const f16*)(ws + WS_W1F_HI) + (size_t)d * 8192;
    const f16* w1fl = (const f16*)(ws + WS_W1F_LO) + (size_t)d * 8192;
    const f16* w1tf = (const f16*)(ws + WS_W1TF)   + (size_t)d * 8192;
    const float* w64p = (const float*)(ws + WS_W64);

    // ---------- stage: x tile (f32 global, L2-hot) split to hi/lo f16 in LDS ----------
    {
        const float4* xs = (const float4*)(x + (size_t)(b * 514 + t0) * 32);
        for (int u = tid; u < 528; u += 256) {          // 66 rows x 8 float4
            float4 v = xs[u];
            int row = u >> 3, c4 = u & 7;
            half4 hi, lo;
            #pragma unroll
            for (int j = 0; j < 4; ++j) {
                float vv = (&v.x)[j];
                f16 h = (f16)vv;
                hi[j] = h;
                lo[j] = (f16)((vv - (float)h) * 4096.0f);
            }
            *(half4*)(smem + L_XSHI + (row * XS_ROW + c4 * 4) * 2) = hi;
            *(half4*)(smem + L_XSLO + (row * XS_ROW + c4 * 4) * 2) = lo;
        }
        if (tid < 128) {
            b1L[tid]  = b1[d * 128 + tid];
            W2L[tid]  = W2[d * 128 + tid];
            w64L[tid] = w64p[d * 128 + tid];
        }
        if (tid < 64) yyL[tid] = x[(size_t)(b * 514 + t0 + tid + 2) * 32 + d];
    }
    __syncthreads();

    float yyv[4];
    #pragma unroll
    for (int nt = 0; nt < 4; ++nt) yyv[nt] = yyL[nt * 16 + c];

    float res[4] = {0.f, 0.f, 0.f, 0.f}, j64[4] = {0.f, 0.f, 0.f, 0.f};

    // ---------- phase 1 in two ht-passes: {24 MFMA -> epilogue} each ----------
    // Halves live accumulators (64 -> 32 regs); acc order per element unchanged.
    #pragma unroll
    for (int ht = 0; ht < 2; ++ht) {
        floatx4 accP[4], accQ[4];
        #pragma unroll
        for (int nt = 0; nt < 4; ++nt) { accP[nt] = (floatx4)0.f; accQ[nt] = (floatx4)0.f; }

        #pragma unroll
        for (int ks = 0; ks < 2; ++ks) {
            const int fo = (((wave * 2 + ht) * 2 + ks) * 64 + lane) * 8;
            const half8 aH = *(const half8*)(w1fh + fo);
            const half8 aL = *(const half8*)(w1fl + fo);
            half8 bH[4], bL[4];
            #pragma unroll
            for (int nt = 0; nt < 4; ++nt) {
                const int off = (nt * 16 + c + ks) * XS_ROW + q * 8;  // window overlap trick
                bH[nt] = *(const half8*)(smem + L_XSHI + off * 2);
                bL[nt] = *(const half8*)(smem + L_XSLO + off * 2);
            }
            #pragma unroll
            for (int nt = 0; nt < 4; ++nt) {
                accP[nt] = __builtin_amdgcn_mfma_f32_16x16x32_f16(aH, bH[nt], accP[nt], 0, 0, 0);
                accQ[nt] = __builtin_amdgcn_mfma_f32_16x16x32_f16(aH, bL[nt], accQ[nt], 0, 0, 0);
                accQ[nt] = __builtin_amdgcn_mfma_f32_16x16x32_f16(aL, bH[nt], accQ[nt], 0, 0, 0);
            }
        }

        // per-ht scalar hoist (short-lived: 16 regs within this pass)
        const int hbase = wave * 32 + ht * 16 + q * 4;   // D row = q*4 + reg
        float b1v[4], W2a[4], W2b[4], w64v[4];
        #pragma unroll
        for (int r = 0; r < 4; ++r) {
            const int h = hbase + r;
            b1v[r]  = b1L[h];
            float w2 = W2L[h];
            W2a[r]  = w2;
            W2b[r]  = 0.01f * w2;
            w64v[r] = w64L[h];
        }

        // epilogue for this ht: pre -> g (LDS, A-layout), res/jac64 partials
        // (GB region disjoint from XS; per-wave columns -> no barrier needed)
        #pragma unroll
        for (int nt = 0; nt < 4; ++nt) {
            const int n = nt * 16 + c;                   // D col = lane&15
            half4 gp;
            #pragma unroll
            for (int r = 0; r < 4; ++r) {
                const float pre = accP[nt][r] + accQ[nt][r] * (1.0f / 4096.0f)
                                + b1v[r] + yyv[nt] * w64v[r];
                const float gg = (pre >= 0.f) ? W2a[r] : W2b[r];
                res[nt] += pre * gg;
                j64[nt] += gg * w64v[r];
                gp[r] = (f16)gg;
            }
            *(half4*)(smem + L_GB + (n * GB_HP + hbase) * 2) = gp;
        }
    }

    #pragma unroll
    for (int nt = 0; nt < 4; ++nt) {
        float rv = res[nt];
        rv += __shfl_xor(rv, 16, 64);
        rv += __shfl_xor(rv, 32, 64);
        float jv = j64[nt];
        jv += __shfl_xor(jv, 16, 64);
        jv += __shfl_xor(jv, 32, 64);
        if (lane < 16) {
            resP[wave * 64 + nt * 16 + lane] = rv;
            jacP[wave * 64 + nt * 16 + lane] = jv;
        }
    }
    __syncthreads();

    // ---------- residuals (d-major, coalesced) + logabsdet (one wave) ----------
    if (tid < 64) {
        const int n = tid;
        float r = b2[d], j = 0.f;
        #pragma unroll
        for (int w = 0; w < 4; ++w) { r += resP[w * 64 + n]; j += jacP[w * 64 + n]; }
        resw[(size_t)d * 32768 + (size_t)(b * 512 + t0) + n] = r;
        float lg = logf(fabsf(j));
        #pragma unroll
        for (int off = 32; off > 0; off >>= 1) lg += __shfl_down(lg, off, 64);
        if (tid == 0) atomicAdd(out + OUT1_OFF + b, lg);
    }

    // ---------- phase 2: jac[n, k<64] = g . W1 ; wave owns one 16-n tile ----------
    // A from LDS (GB), B fragments straight from global (fragment-linear ws).
    floatx4 acc2[4];
    #pragma unroll
    for (int kt = 0; kt < 4; ++kt) acc2[kt] = (floatx4)0.f;
    #pragma unroll
    for (int ks = 0; ks < 4; ++ks) {
        const half8 aF = *(const half8*)(smem + L_GB + ((wave * 16 + c) * GB_HP + ks * 32 + q * 8) * 2);
        half8 bF[4];
        #pragma unroll
        for (int kt = 0; kt < 4; ++kt)
            bF[kt] = *(const half8*)(w1tf + ((ks * 4 + kt) * 64 + lane) * 8);
        #pragma unroll
        for (int kt = 0; kt < 4; ++kt)
            acc2[kt] = __builtin_amdgcn_mfma_f32_16x16x32_f16(aF, bF[kt], acc2[kt], 0, 0, 0);
    }

    // ---------- store: transpose 16x64 tile through own (dead) GB slice,
    //            then 4x contiguous global_store_dwordx4 per lane ----------
    {
        float* tp = (float*)(smem + L_GB + wave * (16 * GB_HP * 2));  // 16 rows, stride 68 f32
        #pragma unroll
        for (int kt = 0; kt < 4; ++kt)
            #pragma unroll
            for (int r = 0; r < 4; ++r)
                tp[(q * 4 + r) * 68 + kt * 16 + c] = acc2[kt][r];
        // same-wave DS ordering + data dependency through acc2: no barrier needed
        float* out2 = out + OUT2_OFF + (size_t)d * ((size_t)32768 * 64)
                    + (size_t)(b * 512 + t0 + wave * 16) * 64;
        #pragma unroll
        for (int j = 0; j < 4; ++j) {
            floatx4 v = *(const floatx4*)(tp + (j * 4 + q) * 68 + c * 4);
            *(floatx4*)(out2 + (size_t)j * 256 + (size_t)lane * 4) = v;
        }
    }
}

// ---- residuals: (d, bn) d-major ws -> (bn, d) out, fully coalesced both sides ----
__global__ __launch_bounds__(256) void finish_res_kernel(
    const float* __restrict__ resw, float* __restrict__ out)
{
    __shared__ float tile[32][65];
    const int n0 = blockIdx.x * 64;   // 512 blocks
    const int tid = threadIdx.x;
    #pragma unroll
    for (int i = 0; i < 8; ++i) {
        int idx = i * 256 + tid;              // 0..2047
        int dd = idx >> 6, n = idx & 63;
        tile[dd][n] = resw[(size_t)dd * 32768 + n0 + n];
    }
    __syncthreads();
    #pragma unroll
    for (int i = 0; i < 8; ++i) {
        int idx = i * 256 + tid;
        int n = idx >> 5, dd = idx & 31;
        out[(size_t)(n0 + n) * 32 + dd] = tile[dd][n];
    }
}

extern "C" void kernel_launch(void* const* d_in, const int* in_sizes, int n_in,
                              void* d_out, int out_size, void* d_ws, size_t ws_size,
                              hipStream_t stream) {
    const float* x  = (const float*)d_in[0];
    const float* W1 = (const float*)d_in[1];
    const float* b1 = (const float*)d_in[2];
    const float* W2 = (const float*)d_in[3];
    const float* b2 = (const float*)d_in[4];
    float* out = (float*)d_out;
    char* ws = (char*)d_ws;

    hipMemsetAsync(out + OUT1_OFF, 0, 64 * sizeof(float), stream);

    hipLaunchKernelGGL(split_w1_kernel, dim3((32 * 128 * 64 + 255) / 256), dim3(256), 0, stream,
                       W1, (f16*)(ws + WS_W1F_HI), (f16*)(ws + WS_W1F_LO),
                       (f16*)(ws + WS_W1TF), (float*)(ws + WS_W64));

    hipLaunchKernelGGL(np_main_kernel, dim3(512, 32), dim3(256), L_TOTAL, stream,
                       x, b1, W2, b2, (const char*)ws, (float*)(ws + WS_RES), out);

    hipLaunchKernelGGL(finish_res_kernel, dim3(512), dim3(256), 0, stream,
                       (const float*)(ws + WS_RES), out);
}